// Round 1
// baseline (455.237 us; speedup 1.0000x reference)
//
#include <hip/hip_runtime.h>

#define SS 2048
#define DD 128
#define NB 16
#define TM 64
#define TN 64
#define NITER (SS / TN)

typedef short bf16x8 __attribute__((ext_vector_type(8)));
typedef float f32x4 __attribute__((ext_vector_type(4)));

#define PSTRIDE 72

// scale * log2(e): softmax base-2 trick (exp2 consistently in num+denom == softmax)
#define SL2E (0.08838834764831845f * 1.4426950408889634f)

__device__ __forceinline__ unsigned short f2bf(float x) {
    unsigned u = __builtin_bit_cast(unsigned, x);
    u += 0x7fffu + ((u >> 16) & 1u);          // RNE
    return (unsigned short)(u >> 16);
}

__device__ __forceinline__ float fexp2(float x) {
#if __has_builtin(__builtin_amdgcn_exp2f)
    return __builtin_amdgcn_exp2f(x);
#else
    return __expf(x * 0.6931471805599453f);
#endif
}

#define LGKM0() asm volatile("s_waitcnt lgkmcnt(0)" ::: "memory")
#define BAR()   __builtin_amdgcn_s_barrier()

// ---- pre-kernel: K fp32->bf16 (x=2,3) and V [B][S][D] -> Vt [B][D][S] bf16 (x=0,1) ----
__global__ void prep_kernel(const float* __restrict__ k, const float* __restrict__ v,
                            unsigned short* __restrict__ kb, unsigned short* __restrict__ vt) {
    __shared__ unsigned short t[64 * 72];
    const int x = blockIdx.x, b = blockIdx.z, sb = blockIdx.y * 64;
    const int tid = threadIdx.x;
    if (x < 2) {
        const int db = x * 64;
        const int r16 = tid >> 4, c4 = (tid & 15) * 4;
        for (int i = 0; i < 4; ++i) {
            int sl = i * 16 + r16;
            float4 xx = *(const float4*)(v + ((size_t)(b * SS + sb + sl) * DD + db + c4));
            ushort4 u; u.x = f2bf(xx.x); u.y = f2bf(xx.y); u.z = f2bf(xx.z); u.w = f2bf(xx.w);
            *(ushort4*)&t[sl * 72 + c4] = u;
        }
        __syncthreads();
        for (int i = 0; i < 4; ++i) {
            int dl = i * 16 + r16;
            ushort4 u;
            u.x = t[(c4 + 0) * 72 + dl];
            u.y = t[(c4 + 1) * 72 + dl];
            u.z = t[(c4 + 2) * 72 + dl];
            u.w = t[(c4 + 3) * 72 + dl];
            *(ushort4*)(vt + ((size_t)(b * DD + db + dl) * SS + sb + c4)) = u;
        }
    } else {
        const int c0 = (x - 2) * 64;
        for (int i = 0; i < 4; ++i) {
            int e = i * 1024 + tid * 4;
            int r = e >> 6, c = e & 63;
            size_t off = (size_t)(b * SS + sb + r) * DD + c0 + c;
            float4 xx = *(const float4*)(k + off);
            ushort4 u; u.x = f2bf(xx.x); u.y = f2bf(xx.y); u.z = f2bf(xx.z); u.w = f2bf(xx.w);
            *(ushort4*)(kb + off) = u;
        }
    }
}

// ---- main fused attention: one 64-row Q-tile per WG, 2 blocks/CU ----
// K/V are L2-resident (XCD-batch swizzle pins 2 MB per XCD L2) -> read MFMA
// fragments DIRECT from global, no K/V LDS staging, no staging barriers.
__global__ __launch_bounds__(512, 4)
void attn_kernel(const float* __restrict__ q,
                 const unsigned short* __restrict__ kb,
                 const unsigned short* __restrict__ vt,
                 float* __restrict__ attn, float* __restrict__ ctx) {
    __shared__ unsigned short P_lds[2][TM * PSTRIDE];   // double-buffered: 1 barrier/iter
    __shared__ float rs_lds[TM];
    __shared__ float inv_lds[TM];

    const int tid = threadIdx.x;
    const int lane = tid & 63, w = tid >> 6;
    const int wm = w >> 2, wn = w & 3;               // 2 row-waves x 4 col-waves
    const int l15 = lane & 15, quad = lane >> 4;

    // XCD-batch swizzle: blocks on XCD x (bid%8) handle batches {2x, 2x+1}
    const int bid = blockIdx.x;
    const int bb = ((bid & 7) << 1) | ((bid >> 3) & 1);
    const int q0 = (bid >> 4) * TM;

    if (tid < TM) rs_lds[tid] = 0.0f;

    // Q fragments from fp32 global, converted in registers. A-layout: m=l15, k=quad*8+j
    bf16x8 qf[2][4];
    {
        const float* qg = q + ((size_t)(bb * SS + q0 + wm * 32 + l15)) * DD + quad * 8;
        for (int mi = 0; mi < 2; ++mi)
            for (int kk = 0; kk < 4; ++kk) {
                float4 a = *(const float4*)(qg + mi * 16 * DD + kk * 32);
                float4 b = *(const float4*)(qg + mi * 16 * DD + kk * 32 + 4);
                bf16x8 f;
                f[0] = (short)f2bf(a.x); f[1] = (short)f2bf(a.y);
                f[2] = (short)f2bf(a.z); f[3] = (short)f2bf(a.w);
                f[4] = (short)f2bf(b.x); f[5] = (short)f2bf(b.y);
                f[6] = (short)f2bf(b.z); f[7] = (short)f2bf(b.w);
                qf[mi][kk] = f;
            }
    }

    const unsigned short* kgb = kb + (size_t)bb * SS * DD;
    const unsigned short* vgb = vt + (size_t)bb * DD * SS;

    // ============ phase A: rowsums of exp2(SL2E * Q K^T) — barrier-free ============
    float rs[8];
    for (int j = 0; j < 8; ++j) rs[j] = 0.0f;
    {
        const unsigned short* kp = kgb + (size_t)(wn * 16 + l15) * DD + quad * 8;
#pragma unroll 2
        for (int it = 0; it < NITER; ++it) {
            f32x4 a0 = (f32x4){0.f, 0.f, 0.f, 0.f};
            f32x4 a1 = (f32x4){0.f, 0.f, 0.f, 0.f};
#pragma unroll
            for (int kk = 0; kk < 4; ++kk) {
                bf16x8 kf = *(const bf16x8*)(kp + kk * 32);
                a0 = __builtin_amdgcn_mfma_f32_16x16x32_bf16(qf[0][kk], kf, a0, 0, 0, 0);
                a1 = __builtin_amdgcn_mfma_f32_16x16x32_bf16(qf[1][kk], kf, a1, 0, 0, 0);
            }
#pragma unroll
            for (int r = 0; r < 4; ++r) {
                rs[r]     += fexp2(a0[r] * SL2E);
                rs[4 + r] += fexp2(a1[r] * SL2E);
            }
            kp += TN * DD;
        }
    }

#pragma unroll
    for (int j = 0; j < 8; ++j) {
        float s = rs[j];
        s += __shfl_xor(s, 1, 64);
        s += __shfl_xor(s, 2, 64);
        s += __shfl_xor(s, 4, 64);
        s += __shfl_xor(s, 8, 64);
        rs[j] = s;
    }
    __syncthreads();   // rs_lds zero-init visible to all waves before atomics
    if (l15 == 0)
        for (int mi = 0; mi < 2; ++mi)
            for (int r = 0; r < 4; ++r)
                atomicAdd(&rs_lds[wm * 32 + mi * 16 + quad * 4 + r], rs[mi * 4 + r]);
    __syncthreads();
    if (tid < TM) inv_lds[tid] = 1.0f / rs_lds[tid];
    __syncthreads();
    float inv[2][4];
    for (int mi = 0; mi < 2; ++mi)
        for (int r = 0; r < 4; ++r)
            inv[mi][r] = inv_lds[wm * 32 + mi * 16 + quad * 4 + r];

    // ============ phase B: attn store + C += P V — 1 barrier/iter ============
    f32x4 cacc[2][2];
    for (int mi = 0; mi < 2; ++mi)
        for (int ni = 0; ni < 2; ++ni) cacc[mi][ni] = (f32x4){0.f, 0.f, 0.f, 0.f};

    float* ab = attn + (size_t)bb * SS * SS
              + (size_t)(q0 + wm * 32) * SS + (wn * 16 + l15);
    const unsigned short* kp0 = kgb + (size_t)(wn * 16 + l15) * DD + quad * 8;
    const unsigned short* vfp = vgb + (size_t)(wn * 32 + l15) * SS + quad * 8;

    // K fragments for it=0, then 1-deep register prefetch each iteration
    bf16x8 kf[4];
#pragma unroll
    for (int kk = 0; kk < 4; ++kk) kf[kk] = *(const bf16x8*)(kp0 + kk * 32);
    const unsigned short* kpn = kp0 + (size_t)TN * DD;

    for (int it = 0; it < NITER; ++it) {
        const int k0 = it * TN;

        // QK^T on current K fragments
        f32x4 acc[2];
        acc[0] = (f32x4){0.f, 0.f, 0.f, 0.f};
        acc[1] = (f32x4){0.f, 0.f, 0.f, 0.f};
        __builtin_amdgcn_s_setprio(1);
#pragma unroll
        for (int kk = 0; kk < 4; ++kk) {
            acc[0] = __builtin_amdgcn_mfma_f32_16x16x32_bf16(qf[0][kk], kf[kk], acc[0], 0, 0, 0);
            acc[1] = __builtin_amdgcn_mfma_f32_16x16x32_bf16(qf[1][kk], kf[kk], acc[1], 0, 0, 0);
        }
        __builtin_amdgcn_s_setprio(0);

        // prefetch next-iteration K fragments (L2-hit; hidden under softmax VALU)
        if (it < NITER - 1) {
#pragma unroll
            for (int kk = 0; kk < 4; ++kk) kf[kk] = *(const bf16x8*)(kpn + kk * 32);
            kpn += (size_t)TN * DD;
        }

        // V fragments for this iteration, direct from global (used after barrier)
        bf16x8 bv[2][2];
#pragma unroll
        for (int kk = 0; kk < 2; ++kk)
#pragma unroll
            for (int ni = 0; ni < 2; ++ni)
                bv[kk][ni] = *(const bf16x8*)(vfp + (size_t)(ni * 16) * SS + k0 + kk * 32);

        // normalized P: fp32 nontemporal to global, bf16 to LDS for PV
        unsigned short* pw = &P_lds[it & 1][0];
#pragma unroll
        for (int mi = 0; mi < 2; ++mi)
#pragma unroll
            for (int r = 0; r < 4; ++r) {
                float p = fexp2(acc[mi][r] * SL2E) * inv[mi][r];
                __builtin_nontemporal_store(p, ab + (size_t)((mi * 16 + quad * 4 + r) * SS) + k0);
                pw[(wm * 32 + mi * 16 + quad * 4 + r) * PSTRIDE + wn * 16 + l15] = f2bf(p);
            }

        LGKM0();   // P writes visible; NO vmcnt drain — stores/prefetch stay in flight
        BAR();

        // PV: C[64 x 128] over 8 waves (wm: 32 rows, wn: 32 d-cols), V from regs
        __builtin_amdgcn_s_setprio(1);
#pragma unroll
        for (int kk = 0; kk < 2; ++kk) {
            bf16x8 af0 = *(const bf16x8*)&pw[(wm * 32 +  0 + l15) * PSTRIDE + kk * 32 + quad * 8];
            bf16x8 af1 = *(const bf16x8*)&pw[(wm * 32 + 16 + l15) * PSTRIDE + kk * 32 + quad * 8];
            cacc[0][0] = __builtin_amdgcn_mfma_f32_16x16x32_bf16(af0, bv[kk][0], cacc[0][0], 0, 0, 0);
            cacc[1][0] = __builtin_amdgcn_mfma_f32_16x16x32_bf16(af1, bv[kk][0], cacc[1][0], 0, 0, 0);
            cacc[0][1] = __builtin_amdgcn_mfma_f32_16x16x32_bf16(af0, bv[kk][1], cacc[0][1], 0, 0, 0);
            cacc[1][1] = __builtin_amdgcn_mfma_f32_16x16x32_bf16(af1, bv[kk][1], cacc[1][1], 0, 0, 0);
        }
        __builtin_amdgcn_s_setprio(0);
        // no second barrier: double-buffered P_lds + barrier rendezvous ordering
        // guarantees no wave's (it+2) writes can precede another wave's (it) reads.
    }

    // epilogue: context (nontemporal, write-once)
    float* cg = ctx + ((size_t)(bb * SS) + q0) * DD;
#pragma unroll
    for (int mi = 0; mi < 2; ++mi)
#pragma unroll
        for (int ni = 0; ni < 2; ++ni)
#pragma unroll
            for (int r = 0; r < 4; ++r) {
                int row = wm * 32 + mi * 16 + quad * 4 + r;
                int col = wn * 32 + ni * 16 + l15;
                __builtin_nontemporal_store(cacc[mi][ni][r], cg + (size_t)row * DD + col);
            }
}

extern "C" void kernel_launch(void* const* d_in, const int* in_sizes, int n_in,
                              void* d_out, int out_size, void* d_ws, size_t ws_size,
                              hipStream_t stream) {
    const float* q = (const float*)d_in[0];
    const float* k = (const float*)d_in[1];
    const float* v = (const float*)d_in[2];
    float* ctx = (float*)d_out;
    float* attn = ctx + (size_t)NB * SS * DD;

    unsigned short* kb = (unsigned short*)d_ws;            // B*S*D bf16
    unsigned short* vt = kb + (size_t)NB * SS * DD;        // [B][D][S] bf16

    prep_kernel<<<dim3(4, SS / 64, NB), 256, 0, stream>>>(k, v, kb, vt);
    attn_kernel<<<dim3((SS / TM) * NB), 512, 0, stream>>>(q, kb, vt, attn, ctx);
}

// Round 2
// 375.485 us; speedup vs baseline: 1.2124x; 1.2124x over previous
//
#include <hip/hip_runtime.h>

#define SS 2048
#define DD 128
#define NB 16
#define TM 64
#define TN 64
#define NITER (SS / TN)

typedef short bf16x8 __attribute__((ext_vector_type(8)));
typedef float f32x4 __attribute__((ext_vector_type(4)));

#define PSTRIDE 72

// scale * log2(e): softmax base-2 trick (exp2 consistently in num+denom == softmax)
#define SL2E (0.08838834764831845f * 1.4426950408889634f)

__device__ __forceinline__ unsigned short f2bf(float x) {
    unsigned u = __builtin_bit_cast(unsigned, x);
    u += 0x7fffu + ((u >> 16) & 1u);          // RNE
    return (unsigned short)(u >> 16);
}

__device__ __forceinline__ float fexp2(float x) {
#if __has_builtin(__builtin_amdgcn_exp2f)
    return __builtin_amdgcn_exp2f(x);
#else
    return __expf(x * 0.6931471805599453f);
#endif
}

#define LGKM0()    asm volatile("s_waitcnt lgkmcnt(0)" ::: "memory")
#define VMCNT(n)   asm volatile("s_waitcnt vmcnt(" #n ")" ::: "memory")
#define BAR()      __builtin_amdgcn_s_barrier()
#define MEMFENCE() asm volatile("" ::: "memory")

// async global->LDS, 16B per lane. LDS dest = wave-uniform base + lane*16 (linear).
__device__ __forceinline__ void gld16(unsigned short* lds, const unsigned short* g) {
    __builtin_amdgcn_global_load_lds(
        (const __attribute__((address_space(1))) void*)g,
        (__attribute__((address_space(3))) void*)lds, 16, 0, 0);
}

// Stage one 64x128 bf16 K tile into a 16KB LDS buffer, XOR-swizzled.
// LDS layout: row r (256B), 16B-slot s holds original slot (s ^ (r&7))  [m173: pre-swizzled source]
__device__ __forceinline__ void stage_k(unsigned short* buf, const unsigned short* kg, int tid) {
#pragma unroll
    for (int c = 0; c < 2; ++c) {
        int e = c * 512 + tid;               // 16B chunk id 0..1023
        int r = e >> 4;                      // row 0..63
        int co = (e & 15) ^ (r & 7);         // original 16B slot
        gld16(buf + e * 8, kg + (size_t)r * DD + co * 8);
    }
}

// Stage one 128x64 bf16 Vt tile (rows = d, 128B each), XOR-swizzled the same way.
__device__ __forceinline__ void stage_v(unsigned short* buf, const unsigned short* vg, int tid) {
#pragma unroll
    for (int c = 0; c < 2; ++c) {
        int e = c * 512 + tid;
        int r = e >> 3;                      // row 0..127
        int co = (e & 7) ^ (r & 7);
        gld16(buf + e * 8, vg + (size_t)r * SS + co * 8);
    }
}

// ---- pre-kernel: K fp32->bf16 (x=2,3) and V [B][S][D] -> Vt [B][D][S] bf16 (x=0,1) ----
__global__ void prep_kernel(const float* __restrict__ k, const float* __restrict__ v,
                            unsigned short* __restrict__ kb, unsigned short* __restrict__ vt) {
    __shared__ unsigned short t[64 * 72];
    const int x = blockIdx.x, b = blockIdx.z, sb = blockIdx.y * 64;
    const int tid = threadIdx.x;
    if (x < 2) {
        const int db = x * 64;
        const int r16 = tid >> 4, c4 = (tid & 15) * 4;
        for (int i = 0; i < 4; ++i) {
            int sl = i * 16 + r16;
            float4 xx = *(const float4*)(v + ((size_t)(b * SS + sb + sl) * DD + db + c4));
            ushort4 u; u.x = f2bf(xx.x); u.y = f2bf(xx.y); u.z = f2bf(xx.z); u.w = f2bf(xx.w);
            *(ushort4*)&t[sl * 72 + c4] = u;
        }
        __syncthreads();
        for (int i = 0; i < 4; ++i) {
            int dl = i * 16 + r16;
            ushort4 u;
            u.x = t[(c4 + 0) * 72 + dl];
            u.y = t[(c4 + 1) * 72 + dl];
            u.z = t[(c4 + 2) * 72 + dl];
            u.w = t[(c4 + 3) * 72 + dl];
            *(ushort4*)(vt + ((size_t)(b * DD + db + dl) * SS + sb + c4)) = u;
        }
    } else {
        const int c0 = (x - 2) * 64;
        for (int i = 0; i < 4; ++i) {
            int e = i * 1024 + tid * 4;
            int r = e >> 6, c = e & 63;
            size_t off = (size_t)(b * SS + sb + r) * DD + c0 + c;
            float4 xx = *(const float4*)(k + off);
            ushort4 u; u.x = f2bf(xx.x); u.y = f2bf(xx.y); u.z = f2bf(xx.z); u.w = f2bf(xx.w);
            *(ushort4*)(kb + off) = u;
        }
    }
}

// ---- main fused attention: one 64-row Q-tile per WG, 2 blocks/CU ----
// Coalesced global_load_lds staging (swizzled), counted vmcnt (stores never drained),
// 1 barrier/iter phase A, 2 barriers/iter phase B.
__global__ __launch_bounds__(512, 4)
void attn_kernel(const float* __restrict__ q,
                 const unsigned short* __restrict__ kb,
                 const unsigned short* __restrict__ vt,
                 float* __restrict__ attn, float* __restrict__ ctx) {
    __shared__ unsigned short KV[4][64 * 128];        // 4 x 16 KB (A: 4xK rotate; B: K0,K1,V0,V1)
    __shared__ unsigned short P_lds[TM * PSTRIDE];    // 9216 B
    __shared__ float rs_lds[TM];
    __shared__ float inv_lds[TM];

    const int tid = threadIdx.x;
    const int lane = tid & 63, w = tid >> 6;
    const int wm = w >> 2, wn = w & 3;               // 2 row-waves x 4 col-waves
    const int l15 = lane & 15, quad = lane >> 4;
    const int sx = (l15 & 7) << 4;                   // swizzle XOR (row&7 == l15&7 for all our reads)

    // XCD-batch swizzle: blocks on XCD x (bid%8) handle batches {2x, 2x+1}
    const int bid = blockIdx.x;
    const int bb = ((bid & 7) << 1) | ((bid >> 3) & 1);
    const int q0 = (bid >> 4) * TM;

    if (tid < TM) rs_lds[tid] = 0.0f;

    // Q fragments from fp32 global, converted in registers. A-layout: m=l15, k=quad*8+j
    bf16x8 qf[2][4];
    {
        const float* qg = q + ((size_t)(bb * SS + q0 + wm * 32 + l15)) * DD + quad * 8;
        for (int mi = 0; mi < 2; ++mi)
            for (int kk = 0; kk < 4; ++kk) {
                float4 a = *(const float4*)(qg + mi * 16 * DD + kk * 32);
                float4 b = *(const float4*)(qg + mi * 16 * DD + kk * 32 + 4);
                bf16x8 f;
                f[0] = (short)f2bf(a.x); f[1] = (short)f2bf(a.y);
                f[2] = (short)f2bf(a.z); f[3] = (short)f2bf(a.w);
                f[4] = (short)f2bf(b.x); f[5] = (short)f2bf(b.y);
                f[6] = (short)f2bf(b.z); f[7] = (short)f2bf(b.w);
                qf[mi][kk] = f;
            }
    }

    const unsigned short* kgb = kb + (size_t)bb * SS * DD;
    const unsigned short* vgb = vt + (size_t)bb * DD * SS;
    const int rK = wn * 16 + l15;                    // K row read by this lane in QK^T

    // ============ phase A: rowsums of exp2(SL2E * Q K^T) ============
    // 4-buffer rotation, 2-tile-deep prefetch, vmcnt(2) per iter (never 0).
    float rs[8];
    for (int j = 0; j < 8; ++j) rs[j] = 0.0f;

    stage_k(&KV[0][0], kgb, tid);
    stage_k(&KV[1][0], kgb + (size_t)TN * DD, tid);
    VMCNT(2);           // tile 0 landed (in-order retirement)
    BAR();

    for (int it = 0; it < NITER; ++it) {
        if (it + 2 < NITER)
            stage_k(&KV[(it + 2) & 3][0], kgb + (size_t)(it + 2) * TN * DD, tid);
        const char* kbuf = (const char*)&KV[it & 3][0];
        f32x4 a0 = (f32x4){0.f, 0.f, 0.f, 0.f};
        f32x4 a1 = (f32x4){0.f, 0.f, 0.f, 0.f};
#pragma unroll
        for (int kk = 0; kk < 4; ++kk) {
            bf16x8 kf = *(const bf16x8*)(kbuf + rK * 256 + ((kk * 64 + quad * 16) ^ sx));
            a0 = __builtin_amdgcn_mfma_f32_16x16x32_bf16(qf[0][kk], kf, a0, 0, 0, 0);
            a1 = __builtin_amdgcn_mfma_f32_16x16x32_bf16(qf[1][kk], kf, a1, 0, 0, 0);
        }
#pragma unroll
        for (int r = 0; r < 4; ++r) {
            rs[r]     += fexp2(a0[r] * SL2E);
            rs[4 + r] += fexp2(a1[r] * SL2E);
        }
        VMCNT(2);       // tile it+1 landed; tile it+2 may still fly
        BAR();
    }

#pragma unroll
    for (int j = 0; j < 8; ++j) {
        float s = rs[j];
        s += __shfl_xor(s, 1, 64);
        s += __shfl_xor(s, 2, 64);
        s += __shfl_xor(s, 4, 64);
        s += __shfl_xor(s, 8, 64);
        rs[j] = s;
    }
    __syncthreads();   // rs_lds zero-init visible before atomics
    if (l15 == 0)
        for (int mi = 0; mi < 2; ++mi)
            for (int r = 0; r < 4; ++r)
                atomicAdd(&rs_lds[wm * 32 + mi * 16 + quad * 4 + r], rs[mi * 4 + r]);
    __syncthreads();
    if (tid < TM) inv_lds[tid] = 1.0f / rs_lds[tid];
    __syncthreads();
    float inv[2][4];
    for (int mi = 0; mi < 2; ++mi)
        for (int r = 0; r < 4; ++r)
            inv[mi][r] = inv_lds[wm * 32 + mi * 16 + quad * 4 + r];

    // ============ phase B: attn store + C += P V ============
    // K double-buffer KV[0..1], V double-buffer KV[2..3].
    // Stage loads issued BEFORE P stores each iter; vmcnt(8) at iter end =>
    // stage loads complete (in-order), the 8 P stores stay in flight across barrier.
    f32x4 cacc[2][2];
    for (int mi = 0; mi < 2; ++mi)
        for (int ni = 0; ni < 2; ++ni) cacc[mi][ni] = (f32x4){0.f, 0.f, 0.f, 0.f};

    float* ab = attn + (size_t)bb * SS * SS
              + (size_t)(q0 + wm * 32) * SS + (wn * 16 + l15);

    stage_k(&KV[0][0], kgb, tid);
    stage_v(&KV[2][0], vgb, tid);
    VMCNT(0);
    BAR();

    for (int it = 0; it < NITER; ++it) {
        const int k0 = it * TN;
        if (it + 1 < NITER) {
            stage_k(&KV[(it + 1) & 1][0], kgb + (size_t)(k0 + TN) * DD, tid);
            stage_v(&KV[2 + ((it + 1) & 1)][0], vgb + (k0 + TN), tid);
        }
        MEMFENCE();    // keep the stores below the 4 stage loads (vmcnt(8) counts on this)

        const char* kbuf = (const char*)&KV[it & 1][0];
        const char* vbuf = (const char*)&KV[2 + (it & 1)][0];

        f32x4 acc[2];
        acc[0] = (f32x4){0.f, 0.f, 0.f, 0.f};
        acc[1] = (f32x4){0.f, 0.f, 0.f, 0.f};
        __builtin_amdgcn_s_setprio(1);
#pragma unroll
        for (int kk = 0; kk < 4; ++kk) {
            bf16x8 kf = *(const bf16x8*)(kbuf + rK * 256 + ((kk * 64 + quad * 16) ^ sx));
            acc[0] = __builtin_amdgcn_mfma_f32_16x16x32_bf16(qf[0][kk], kf, acc[0], 0, 0, 0);
            acc[1] = __builtin_amdgcn_mfma_f32_16x16x32_bf16(qf[1][kk], kf, acc[1], 0, 0, 0);
        }
        __builtin_amdgcn_s_setprio(0);

        // normalized P: fp32 nontemporal to global, bf16 to LDS for PV
#pragma unroll
        for (int mi = 0; mi < 2; ++mi)
#pragma unroll
            for (int r = 0; r < 4; ++r) {
                float p = fexp2(acc[mi][r] * SL2E) * inv[mi][r];
                __builtin_nontemporal_store(p, ab + (size_t)((mi * 16 + quad * 4 + r) * SS) + k0);
                P_lds[(wm * 32 + mi * 16 + quad * 4 + r) * PSTRIDE + wn * 16 + l15] = f2bf(p);
            }

        LGKM0();       // own P writes committed to LDS
        BAR();         // all waves' P visible; V tile already validated last iter

        // PV: C[64 x 128] over 8 waves (wm: 32 rows, wn: 32 d-cols)
        __builtin_amdgcn_s_setprio(1);
#pragma unroll
        for (int kk = 0; kk < 2; ++kk) {
            bf16x8 af0 = *(const bf16x8*)&P_lds[(wm * 32 +  0 + l15) * PSTRIDE + kk * 32 + quad * 8];
            bf16x8 af1 = *(const bf16x8*)&P_lds[(wm * 32 + 16 + l15) * PSTRIDE + kk * 32 + quad * 8];
            const int vc = kk * 64 + quad * 16;
            bf16x8 bv0 = *(const bf16x8*)(vbuf + (wn * 32 +  0 + l15) * 128 + (vc ^ sx));
            bf16x8 bv1 = *(const bf16x8*)(vbuf + (wn * 32 + 16 + l15) * 128 + (vc ^ sx));
            cacc[0][0] = __builtin_amdgcn_mfma_f32_16x16x32_bf16(af0, bv0, cacc[0][0], 0, 0, 0);
            cacc[1][0] = __builtin_amdgcn_mfma_f32_16x16x32_bf16(af1, bv0, cacc[1][0], 0, 0, 0);
            cacc[0][1] = __builtin_amdgcn_mfma_f32_16x16x32_bf16(af0, bv1, cacc[0][1], 0, 0, 0);
            cacc[1][1] = __builtin_amdgcn_mfma_f32_16x16x32_bf16(af1, bv1, cacc[1][1], 0, 0, 0);
        }
        __builtin_amdgcn_s_setprio(0);

        VMCNT(8);      // 4 stage loads retired (issued before the 8 stores); stores stay in flight
        BAR();         // all waves done reading this iter's buffers -> safe to overwrite
    }

    // epilogue: context (nontemporal, write-once)
    float* cg = ctx + ((size_t)(bb * SS) + q0) * DD;
#pragma unroll
    for (int mi = 0; mi < 2; ++mi)
#pragma unroll
        for (int ni = 0; ni < 2; ++ni)
#pragma unroll
            for (int r = 0; r < 4; ++r) {
                int row = wm * 32 + mi * 16 + quad * 4 + r;
                int col = wn * 32 + ni * 16 + l15;
                __builtin_nontemporal_store(cacc[mi][ni][r], cg + (size_t)row * DD + col);
            }
}

extern "C" void kernel_launch(void* const* d_in, const int* in_sizes, int n_in,
                              void* d_out, int out_size, void* d_ws, size_t ws_size,
                              hipStream_t stream) {
    const float* q = (const float*)d_in[0];
    const float* k = (const float*)d_in[1];
    const float* v = (const float*)d_in[2];
    float* ctx = (float*)d_out;
    float* attn = ctx + (size_t)NB * SS * DD;

    unsigned short* kb = (unsigned short*)d_ws;            // B*S*D bf16
    unsigned short* vt = kb + (size_t)NB * SS * DD;        // [B][D][S] bf16

    prep_kernel<<<dim3(4, SS / 64, NB), 256, 0, stream>>>(k, v, kb, vt);
    attn_kernel<<<dim3((SS / TM) * NB), 512, 0, stream>>>(q, kb, vt, attn, ctx);
}